// Round 2
// baseline (2798.026 us; speedup 1.0000x reference)
//
#include <hip/hip_runtime.h>

static constexpr int F_IN = 128;
static constexpr int H1 = 32;
static constexpr int H2 = 64;
static constexpr int TPB = 256;

// ---------------- degree / dinv ----------------
__global__ void deg_kernel(const int* __restrict__ dst, float* __restrict__ deg, int E) {
    for (int i = blockIdx.x * blockDim.x + threadIdx.x; i < E; i += gridDim.x * blockDim.x)
        atomicAdd(&deg[dst[i]], 1.0f);
}

__global__ void dinv_kernel(float* __restrict__ d, int N) {
    int i = blockIdx.x * blockDim.x + threadIdx.x;
    if (i < N) d[i] = 1.0f / sqrtf(d[i] + 1.0f);  // deg incl. self-loop
}

// ---------------- fold W3 @ W_lin -> w3l[64], beta = b3.W_lin + b_lin ----------------
__global__ void prep_kernel(const float* __restrict__ W3, const float* __restrict__ b3,
                            const float* __restrict__ Wl, const float* __restrict__ bl,
                            float* __restrict__ w3l) {
    int j = threadIdx.x;  // 64 threads
    float acc = 0.0f;
#pragma unroll
    for (int k = 0; k < 128; ++k) acc = fmaf(W3[j * 128 + k], Wl[k], acc);
    w3l[j] = acc;
    if (j == 0) {
        float beta = bl[0];
        for (int f = 0; f < 128; ++f) beta = fmaf(b3[f], Wl[f], beta);
        w3l[64] = beta;
    }
}

// ---------------- GEMM with fused self-loop epilogue ----------------
// main = MAIN_BIAS_RELU ? relu(acc + b[c]) : acc          -> T
// aux  = MAIN_BIAS_RELU ? main*d^2        : main*d^2+b[c] -> AUX  (self-loop init)
template <int FIN, int FOUT, bool MAIN_BIAS_RELU>
__global__ void gemm_fused(const float* __restrict__ X, const float* __restrict__ W,
                           const float* __restrict__ b, const float* __restrict__ dinv,
                           float* __restrict__ T, float* __restrict__ AUX, int N) {
    __shared__ float Ws[FIN * FOUT];
    for (int t = threadIdx.x; t < FIN * FOUT; t += blockDim.x) Ws[t] = W[t];
    __syncthreads();
    constexpr int ROWS = TPB / FOUT;
    const int c = threadIdx.x % FOUT;
    const int r = threadIdx.x / FOUT;
    for (int base = blockIdx.x * ROWS; base < N; base += gridDim.x * ROWS) {
        int row = base + r;
        if (row >= N) continue;
        const float* xr = X + (long)row * FIN;
        float acc = 0.0f;
#pragma unroll
        for (int k = 0; k < FIN; ++k) acc = fmaf(xr[k], Ws[k * FOUT + c], acc);
        float d = dinv[row];
        float d2 = d * d;
        float mainv, auxv;
        if (MAIN_BIAS_RELU) {
            mainv = fmaxf(acc + b[c], 0.0f);
            auxv = mainv * d2;
        } else {
            mainv = acc;
            auxv = fmaf(acc, d2, b[c]);
        }
        T[(long)row * FOUT + c] = mainv;
        AUX[(long)row * FOUT + c] = auxv;
    }
}

// ---------------- self-loop init with relu on input: S = relu(G)*dinv^2 ----------------
template <int F>
__global__ void init_relu(const float* __restrict__ Gin, const float* __restrict__ dinv,
                          float* __restrict__ S, int N) {
    const unsigned total = (unsigned)N * F;
    for (unsigned t = blockIdx.x * blockDim.x + threadIdx.x; t < total;
         t += gridDim.x * blockDim.x) {
        unsigned i = t / F;
        float d = dinv[i];
        S[t] = fmaxf(Gin[t], 0.0f) * d * d;
    }
}

// ---------------- edge scatter (float4/thread): G[dst] += relu?(H[src]) * coef ----------------
template <int F, bool RELU>
__global__ void scatter4(const int* __restrict__ src, const int* __restrict__ dst,
                         const float* __restrict__ dinv, const float* __restrict__ H,
                         float* __restrict__ G, int E) {
    constexpr int PE = F / 4;  // float4 chunks per edge
    const unsigned total = (unsigned)E * PE;
    for (unsigned t = blockIdx.x * blockDim.x + threadIdx.x; t < total;
         t += gridDim.x * blockDim.x) {
        unsigned e = t / PE;
        unsigned q = t % PE;
        int s = src[e], d = dst[e];
        float coef = dinv[s] * dinv[d];
        float4 v = *reinterpret_cast<const float4*>(H + (unsigned)s * F + q * 4);
        if (RELU) {
            v.x = fmaxf(v.x, 0.0f); v.y = fmaxf(v.y, 0.0f);
            v.z = fmaxf(v.z, 0.0f); v.w = fmaxf(v.w, 0.0f);
        }
        float* base = G + (unsigned)d * F + q * 4;
        atomicAdd(base + 0, v.x * coef);
        atomicAdd(base + 1, v.y * coef);
        atomicAdd(base + 2, v.z * coef);
        atomicAdd(base + 3, v.w * coef);
    }
}

// ---------------- per-node dot with w3l + segment sum/count by (sorted) batch ----------------
__global__ void dot_pool_kernel(const float* __restrict__ S2, const float* __restrict__ w3l,
                                const int* __restrict__ batch, float* __restrict__ sums,
                                float* __restrict__ cnt, int N, int G) {
    __shared__ float wl[64];
    __shared__ float accS[256];
    __shared__ float cntS[256];
    if (threadIdx.x < 64) wl[threadIdx.x] = w3l[threadIdx.x];
    accS[threadIdx.x] = 0.0f;
    cntS[threadIdx.x] = 0.0f;
    __syncthreads();
    int i = blockIdx.x * blockDim.x + threadIdx.x;
    int first = blockIdx.x * blockDim.x;
    int b0 = batch[first < N ? first : (N - 1)];
    if (i < N) {
        const float4* row = reinterpret_cast<const float4*>(S2 + (unsigned)i * 64);
        float t = 0.0f;
#pragma unroll
        for (int k = 0; k < 16; ++k) {
            float4 v = row[k];
            t = fmaf(v.x, wl[k * 4 + 0], t);
            t = fmaf(v.y, wl[k * 4 + 1], t);
            t = fmaf(v.z, wl[k * 4 + 2], t);
            t = fmaf(v.w, wl[k * 4 + 3], t);
        }
        int off = batch[i] - b0;
        if (off < 256) {
            atomicAdd(&accS[off], t);
            atomicAdd(&cntS[off], 1.0f);
        } else {
            atomicAdd(&sums[batch[i]], t);
            atomicAdd(&cnt[batch[i]], 1.0f);
        }
    }
    __syncthreads();
    int g = b0 + threadIdx.x;
    if (g < G) {
        if (accS[threadIdx.x] != 0.0f) atomicAdd(&sums[g], accS[threadIdx.x]);
        if (cntS[threadIdx.x] != 0.0f) atomicAdd(&cnt[g], cntS[threadIdx.x]);
    }
}

// ---------------- out[g] = sums/max(cnt,1) + beta ----------------
__global__ void out_kernel(const float* __restrict__ sums, const float* __restrict__ cnt,
                           const float* __restrict__ w3l, float* __restrict__ out, int G) {
    int g = blockIdx.x * blockDim.x + threadIdx.x;
    if (g < G) out[g] = sums[g] / fmaxf(cnt[g], 1.0f) + w3l[64];
}

static inline int grid_for(unsigned total, int cap = 8192) {
    unsigned g = (total + TPB - 1) / TPB;
    return (int)(g < (unsigned)cap ? g : (unsigned)cap);
}

extern "C" void kernel_launch(void* const* d_in, const int* in_sizes, int n_in,
                              void* d_out, int out_size, void* d_ws, size_t ws_size,
                              hipStream_t stream) {
    const float* x     = (const float*)d_in[0];
    const int*   ei    = (const int*)d_in[1];
    const int*   batch = (const int*)d_in[2];
    const float* W1    = (const float*)d_in[3];
    const float* b1    = (const float*)d_in[4];
    const float* W2    = (const float*)d_in[5];
    const float* b2    = (const float*)d_in[6];
    const float* W3    = (const float*)d_in[7];
    const float* b3    = (const float*)d_in[8];
    const float* Wl    = (const float*)d_in[9];
    const float* bl    = (const float*)d_in[10];
    float* out = (float*)d_out;

    const int N = in_sizes[0] / F_IN;  // 100000
    const int E = in_sizes[1] / 2;     // 1600000
    const int G = out_size;            // 1024
    const int* src = ei;
    const int* dst = ei + E;

    // workspace layout (floats)
    float* dinv = (float*)d_ws;                 // N
    float* t1   = dinv + N;                     // N*32
    float* g1   = t1 + (size_t)N * H1;          // N*32
    float* s1   = g1 + (size_t)N * H1;          // N*32
    float* h2   = s1 + (size_t)N * H1;          // N*64
    float* s2   = h2 + (size_t)N * H2;          // N*64
    float* w3l  = s2 + (size_t)N * H2;          // 65 (w3l[64] = beta)
    float* sums = w3l + 72;                     // G
    float* cnt  = sums + G;                     // G

    hipMemsetAsync(dinv, 0, (size_t)N * sizeof(float), stream);
    hipMemsetAsync(sums, 0, (size_t)2 * G * sizeof(float), stream);

    // degree -> dinv
    deg_kernel<<<grid_for(E), TPB, 0, stream>>>(dst, dinv, E);
    dinv_kernel<<<(N + TPB - 1) / TPB, TPB, 0, stream>>>(dinv, N);

    // fold last layer + head
    prep_kernel<<<1, 64, 0, stream>>>(W3, b3, Wl, bl, w3l);

    // L1: t1 = x@W1 ; g1 = t1*d^2 + b1 ; g1 += scatter(t1)
    gemm_fused<F_IN, H1, false><<<grid_for((unsigned)N * H1), TPB, 0, stream>>>(
        x, W1, b1, dinv, t1, g1, N);
    scatter4<H1, false><<<grid_for((unsigned)E * (H1 / 4)), TPB, 0, stream>>>(
        src, dst, dinv, t1, g1, E);

    // L2 aggregate: s1 = relu(g1)*d^2 ; s1 += scatter(relu(g1))
    init_relu<H1><<<grid_for((unsigned)N * H1), TPB, 0, stream>>>(g1, dinv, s1, N);
    scatter4<H1, true><<<grid_for((unsigned)E * (H1 / 4)), TPB, 0, stream>>>(
        src, dst, dinv, g1, s1, E);

    // L2 transform: h2 = relu(s1@W2 + b2) ; s2 = h2*d^2
    gemm_fused<H1, H2, true><<<grid_for((unsigned)N * H2), TPB, 0, stream>>>(
        s1, W2, b2, dinv, h2, s2, N);

    // L3 aggregate: s2 += scatter(h2)
    scatter4<H2, false><<<grid_for((unsigned)E * (H2 / 4)), TPB, 0, stream>>>(
        src, dst, dinv, h2, s2, E);

    // fused dot(w3l) + segment mean + head
    dot_pool_kernel<<<(N + TPB - 1) / TPB, TPB, 0, stream>>>(s2, w3l, batch, sums, cnt, N, G);
    out_kernel<<<(G + TPB - 1) / TPB, TPB, 0, stream>>>(sums, cnt, w3l, out, G);
}

// Round 3
// 624.147 us; speedup vs baseline: 4.4830x; 4.4830x over previous
//
#include <hip/hip_runtime.h>

static constexpr int F_IN = 128;
static constexpr int H1 = 32;
static constexpr int TPB = 256;

// ---------------- degree / dinv ----------------
__global__ void deg_kernel(const int* __restrict__ dst, float* __restrict__ deg, int E) {
    for (int i = blockIdx.x * blockDim.x + threadIdx.x; i < E; i += gridDim.x * blockDim.x)
        atomicAdd(&deg[dst[i]], 1.0f);
}

__global__ void dinv_kernel(float* __restrict__ d, int N) {
    int i = blockIdx.x * blockDim.x + threadIdx.x;
    if (i < N) d[i] = 1.0f / sqrtf(d[i] + 1.0f);  // deg incl. self-loop
}

// ---------------- fold W3 @ W_lin -> w3l[64], w3l[64]=beta = b3.W_lin + b_lin ----------------
__global__ void prep_kernel(const float* __restrict__ W3, const float* __restrict__ b3,
                            const float* __restrict__ Wl, const float* __restrict__ bl,
                            float* __restrict__ w3l) {
    int j = threadIdx.x;  // 64 threads
    float acc = 0.0f;
#pragma unroll
    for (int k = 0; k < 128; ++k) acc = fmaf(W3[j * 128 + k], Wl[k], acc);
    w3l[j] = acc;
    if (j == 0) {
        float beta = bl[0];
        for (int f = 0; f < 128; ++f) beta = fmaf(b3[f], Wl[f], beta);
        w3l[64] = beta;
    }
}

// ---------------- L1 GEMM: t1 = x@W1 ; g1 = t1*d^2 + b1 (self-loop init) ----------------
__global__ void gemm1_fused(const float* __restrict__ X, const float* __restrict__ W,
                            const float* __restrict__ b, const float* __restrict__ dinv,
                            float* __restrict__ T, float* __restrict__ AUX, int N) {
    __shared__ float Ws[F_IN * H1];
    for (int t = threadIdx.x; t < F_IN * H1; t += blockDim.x) Ws[t] = W[t];
    __syncthreads();
    constexpr int ROWS = TPB / H1;  // 8
    const int c = threadIdx.x % H1;
    const int r = threadIdx.x / H1;
    const float bias = b[c];
    for (int base = blockIdx.x * ROWS; base < N; base += gridDim.x * ROWS) {
        int row = base + r;
        if (row >= N) continue;
        const float* xr = X + (long)row * F_IN;
        float acc = 0.0f;
#pragma unroll
        for (int k = 0; k < F_IN; ++k) acc = fmaf(xr[k], Ws[k * H1 + c], acc);
        float d = dinv[row];
        T[(long)row * H1 + c] = acc;
        AUX[(long)row * H1 + c] = fmaf(acc, d * d, bias);
    }
}

// ---------------- self-loop init with relu on input: S = relu(G)*dinv^2 ----------------
__global__ void init_relu(const float* __restrict__ Gin, const float* __restrict__ dinv,
                          float* __restrict__ S, int N) {
    const unsigned total = (unsigned)N * H1;
    for (unsigned t = blockIdx.x * blockDim.x + threadIdx.x; t < total;
         t += gridDim.x * blockDim.x) {
        unsigned i = t >> 5;
        float d = dinv[i];
        S[t] = fmaxf(Gin[t], 0.0f) * d * d;
    }
}

// ---------------- edge scatter, element-per-thread (lane-contiguous within a row) ----------
template <bool RELU>
__global__ void scatter_elem(const int* __restrict__ src, const int* __restrict__ dst,
                             const float* __restrict__ dinv, const float* __restrict__ H,
                             float* __restrict__ G, int E) {
    const unsigned total = (unsigned)E * H1;
    for (unsigned t = blockIdx.x * blockDim.x + threadIdx.x; t < total;
         t += gridDim.x * blockDim.x) {
        unsigned e = t >> 5;   // H1 == 32
        unsigned f = t & 31;
        int s = src[e], d = dst[e];
        float coef = dinv[s] * dinv[d];
        float v = H[(unsigned)s * H1 + f];
        if (RELU) v = fmaxf(v, 0.0f);
        atomicAdd(&G[(unsigned)d * H1 + f], v * coef);
    }
}

// ---------------- L2 GEMM (32->64) with fused z = relu(acc+b2) . w3l epilogue ------------
__global__ void gemm2_z(const float* __restrict__ S1, const float* __restrict__ W2,
                        const float* __restrict__ b2, const float* __restrict__ w3l,
                        const float* __restrict__ dinv, float* __restrict__ z,
                        float* __restrict__ sz, int N) {
    __shared__ float Ws[H1 * 64];
    for (int t = threadIdx.x; t < H1 * 64; t += blockDim.x) Ws[t] = W2[t];
    __syncthreads();
    const int c = threadIdx.x & 63;   // one wave per row
    const int r = threadIdx.x >> 6;   // 4 rows per block
    const float wl = w3l[c];
    const float bias = b2[c];
    for (int base = blockIdx.x * 4; base < N; base += gridDim.x * 4) {
        int row = base + r;
        if (row >= N) continue;
        const float* xr = S1 + (long)row * H1;
        float acc = 0.0f;
#pragma unroll
        for (int k = 0; k < H1; ++k) acc = fmaf(xr[k], Ws[k * 64 + c], acc);
        float p = fmaxf(acc + bias, 0.0f) * wl;  // x3[row,c] * w3l[c]
#pragma unroll
        for (int o = 32; o > 0; o >>= 1) p += __shfl_down(p, o);
        if (c == 0) {
            z[row] = p;
            float d = dinv[row];
            sz[row] = p * d * d;  // self-loop term
        }
    }
}

// ---------------- scalar edge scatter for layer 3 ----------------
__global__ void scatter_scalar(const int* __restrict__ src, const int* __restrict__ dst,
                               const float* __restrict__ dinv, const float* __restrict__ z,
                               float* __restrict__ sz, int E) {
    for (int i = blockIdx.x * blockDim.x + threadIdx.x; i < E; i += gridDim.x * blockDim.x) {
        int s = src[i], d = dst[i];
        atomicAdd(&sz[d], z[s] * dinv[s] * dinv[d]);
    }
}

// ---------------- segment mean of scalar per node (batch sorted) ----------------
__global__ void pool_scalar(const float* __restrict__ sz, const int* __restrict__ batch,
                            float* __restrict__ sums, float* __restrict__ cnt, int N, int G) {
    __shared__ float accS[TPB];
    __shared__ float cntS[TPB];
    accS[threadIdx.x] = 0.0f;
    cntS[threadIdx.x] = 0.0f;
    __syncthreads();
    int i = blockIdx.x * blockDim.x + threadIdx.x;
    int first = blockIdx.x * blockDim.x;
    int b0 = batch[first < N ? first : (N - 1)];
    if (i < N) {
        int off = batch[i] - b0;
        if (off < TPB) {
            atomicAdd(&accS[off], sz[i]);
            atomicAdd(&cntS[off], 1.0f);
        } else {
            atomicAdd(&sums[batch[i]], sz[i]);
            atomicAdd(&cnt[batch[i]], 1.0f);
        }
    }
    __syncthreads();
    int g = b0 + threadIdx.x;
    if (g < G) {
        if (accS[threadIdx.x] != 0.0f) atomicAdd(&sums[g], accS[threadIdx.x]);
        if (cntS[threadIdx.x] != 0.0f) atomicAdd(&cnt[g], cntS[threadIdx.x]);
    }
}

__global__ void out_kernel(const float* __restrict__ sums, const float* __restrict__ cnt,
                           const float* __restrict__ w3l, float* __restrict__ out, int G) {
    int g = blockIdx.x * blockDim.x + threadIdx.x;
    if (g < G) out[g] = sums[g] / fmaxf(cnt[g], 1.0f) + w3l[64];
}

static inline int grid_for(unsigned total, int cap = 8192) {
    unsigned g = (total + TPB - 1) / TPB;
    return (int)(g < (unsigned)cap ? g : (unsigned)cap);
}

extern "C" void kernel_launch(void* const* d_in, const int* in_sizes, int n_in,
                              void* d_out, int out_size, void* d_ws, size_t ws_size,
                              hipStream_t stream) {
    const float* x     = (const float*)d_in[0];
    const int*   ei    = (const int*)d_in[1];
    const int*   batch = (const int*)d_in[2];
    const float* W1    = (const float*)d_in[3];
    const float* b1    = (const float*)d_in[4];
    const float* W2    = (const float*)d_in[5];
    const float* b2    = (const float*)d_in[6];
    const float* W3    = (const float*)d_in[7];
    const float* b3    = (const float*)d_in[8];
    const float* Wl    = (const float*)d_in[9];
    const float* bl    = (const float*)d_in[10];
    float* out = (float*)d_out;

    const int N = in_sizes[0] / F_IN;  // 100000
    const int E = in_sizes[1] / 2;     // 1600000
    const int G = out_size;            // 1024
    const int* src = ei;
    const int* dst = ei + E;

    // workspace layout (floats)
    float* dinv = (float*)d_ws;                 // N
    float* t1   = dinv + N;                     // N*32
    float* g1   = t1 + (size_t)N * H1;          // N*32
    float* s1   = g1 + (size_t)N * H1;          // N*32
    float* z    = s1 + (size_t)N * H1;          // N
    float* sz   = z + N;                        // N
    float* w3l  = sz + N;                       // 65 (w3l[64] = beta)
    float* sums = w3l + 72;                     // G
    float* cnt  = sums + G;                     // G

    hipMemsetAsync(dinv, 0, (size_t)N * sizeof(float), stream);
    hipMemsetAsync(sums, 0, (size_t)2 * G * sizeof(float), stream);

    // degree -> dinv
    deg_kernel<<<grid_for(E), TPB, 0, stream>>>(dst, dinv, E);
    dinv_kernel<<<(N + TPB - 1) / TPB, TPB, 0, stream>>>(dinv, N);

    // fold last layer + head
    prep_kernel<<<1, 64, 0, stream>>>(W3, b3, Wl, bl, w3l);

    // L1: t1 = x@W1 ; g1 = t1*d^2 + b1 ; g1 += scatter(t1)
    gemm1_fused<<<grid_for((unsigned)N * H1), TPB, 0, stream>>>(x, W1, b1, dinv, t1, g1, N);
    scatter_elem<false><<<grid_for((unsigned)E * H1), TPB, 0, stream>>>(src, dst, dinv, t1, g1, E);

    // L2 aggregate: s1 = relu(g1)*d^2 ; s1 += scatter(relu(g1))
    init_relu<<<grid_for((unsigned)N * H1), TPB, 0, stream>>>(g1, dinv, s1, N);
    scatter_elem<true><<<grid_for((unsigned)E * H1), TPB, 0, stream>>>(src, dst, dinv, g1, s1, E);

    // L2 transform + head fold: z = relu(s1@W2+b2).w3l ; sz = z*d^2
    gemm2_z<<<grid_for((unsigned)N * 64), TPB, 0, stream>>>(s1, W2, b2, w3l, dinv, z, sz, N);

    // L3 aggregate (scalar): sz[dst] += z[src]*coef
    scatter_scalar<<<grid_for(E), TPB, 0, stream>>>(src, dst, dinv, z, sz, E);

    // segment mean + beta
    pool_scalar<<<(N + TPB - 1) / TPB, TPB, 0, stream>>>(sz, batch, sums, cnt, N, G);
    out_kernel<<<(G + TPB - 1) / TPB, TPB, 0, stream>>>(sums, cnt, w3l, out, G);
}

// Round 4
// 422.531 us; speedup vs baseline: 6.6221x; 1.4772x over previous
//
#include <hip/hip_runtime.h>

static constexpr int F_IN = 128;
static constexpr int H1 = 32;
static constexpr int TPB = 256;

// ---------------- degree count (int) ----------------
__global__ void deg_kernel(const int* __restrict__ dst, int* __restrict__ degi, int E) {
    for (int i = blockIdx.x * blockDim.x + threadIdx.x; i < E; i += gridDim.x * blockDim.x)
        atomicAdd(&degi[dst[i]], 1);
}

// ---------------- prefix scan (3 passes) for CSR rowptr ----------------
__global__ void scan1(const int* __restrict__ degi, int* __restrict__ bsum, int N) {
    __shared__ int sh[TPB];
    int i = blockIdx.x * TPB + threadIdx.x;
    sh[threadIdx.x] = (i < N) ? degi[i] : 0;
    __syncthreads();
    for (int o = TPB / 2; o > 0; o >>= 1) {
        if (threadIdx.x < o) sh[threadIdx.x] += sh[threadIdx.x + o];
        __syncthreads();
    }
    if (threadIdx.x == 0) bsum[blockIdx.x] = sh[0];
}

__global__ void scan2(int* __restrict__ bsum, int nb) {  // nb <= 512, one block of 512
    __shared__ int sh[512];
    int t = threadIdx.x;
    int orig = (t < nb) ? bsum[t] : 0;
    sh[t] = orig;
    __syncthreads();
    for (int o = 1; o < 512; o <<= 1) {
        int v = (t >= o) ? sh[t - o] : 0;
        __syncthreads();
        sh[t] += v;
        __syncthreads();
    }
    if (t < nb) bsum[t] = sh[t] - orig;  // exclusive
}

__global__ void scan3(const int* __restrict__ degi, const int* __restrict__ bsum,
                      int* __restrict__ rowptr, int* __restrict__ cursor,
                      float* __restrict__ dinv, int N) {
    __shared__ int sh[TPB];
    int i = blockIdx.x * TPB + threadIdx.x;
    int t = threadIdx.x;
    int d = (i < N) ? degi[i] : 0;
    sh[t] = d;
    __syncthreads();
    for (int o = 1; o < TPB; o <<= 1) {
        int v = (t >= o) ? sh[t - o] : 0;
        __syncthreads();
        sh[t] += v;
        __syncthreads();
    }
    if (i < N) {
        int excl = sh[t] - d + bsum[blockIdx.x];
        rowptr[i] = excl;
        cursor[i] = excl;
        dinv[i] = 1.0f / sqrtf((float)d + 1.0f);  // deg incl. self-loop
    }
}

// ---------------- CSR fill: bucket edges by dst, precompute coef ----------------
__global__ void fill_kernel(const int* __restrict__ src, const int* __restrict__ dst,
                            const float* __restrict__ dinv, int* __restrict__ cursor,
                            int* __restrict__ csr_src, float* __restrict__ csr_coef, int E) {
    for (int i = blockIdx.x * blockDim.x + threadIdx.x; i < E; i += gridDim.x * blockDim.x) {
        int s = src[i], d = dst[i];
        int slot = atomicAdd(&cursor[d], 1);
        csr_src[slot] = s;
        csr_coef[slot] = dinv[s] * dinv[d];
    }
}

// ---------------- fold W3 @ W_lin -> w3l[64], w3l[64] = beta ----------------
__global__ void prep_kernel(const float* __restrict__ W3, const float* __restrict__ b3,
                            const float* __restrict__ Wl, const float* __restrict__ bl,
                            float* __restrict__ w3l) {
    int j = threadIdx.x;  // 64 threads
    float acc = 0.0f;
#pragma unroll
    for (int k = 0; k < 128; ++k) acc = fmaf(W3[j * 128 + k], Wl[k], acc);
    w3l[j] = acc;
    if (j == 0) {
        float beta = bl[0];
        for (int f = 0; f < 128; ++f) beta = fmaf(b3[f], Wl[f], beta);
        w3l[64] = beta;
    }
}

// ---------------- L1 GEMM: t1 = x@W1 (no bias; bias enters via gather init) ----------------
__global__ void gemm1_kernel(const float* __restrict__ X, const float* __restrict__ W,
                             float* __restrict__ T, int N) {
    __shared__ float Ws[F_IN * H1];
    for (int t = threadIdx.x; t < F_IN * H1; t += blockDim.x) Ws[t] = W[t];
    __syncthreads();
    constexpr int ROWS = TPB / H1;  // 8
    const int c = threadIdx.x % H1;
    const int r = threadIdx.x / H1;
    for (int base = blockIdx.x * ROWS; base < N; base += gridDim.x * ROWS) {
        int row = base + r;
        if (row >= N) continue;
        const float4* xr = reinterpret_cast<const float4*>(X + (size_t)row * F_IN);
        float acc = 0.0f;
#pragma unroll
        for (int k4 = 0; k4 < F_IN / 4; ++k4) {
            float4 xv = xr[k4];
            acc = fmaf(xv.x, Ws[(k4 * 4 + 0) * H1 + c], acc);
            acc = fmaf(xv.y, Ws[(k4 * 4 + 1) * H1 + c], acc);
            acc = fmaf(xv.z, Ws[(k4 * 4 + 2) * H1 + c], acc);
            acc = fmaf(xv.w, Ws[(k4 * 4 + 3) * H1 + c], acc);
        }
        T[(size_t)row * H1 + c] = acc;
    }
}

// ---------------- CSR gather aggregation (32 lanes per dst node, no atomics) -------------
// RELU=false: out[d,f] = H[d,f]*dv^2 + b[f] + sum relu?(H[s,f])*coef
// RELU=true : out[d,f] = relu(H[d,f])*dv^2 + sum relu(H[s,f])*coef
template <bool RELU>
__global__ void gather32(const int* __restrict__ rowptr, const int* __restrict__ degi,
                         const int* __restrict__ csr_src, const float* __restrict__ csr_coef,
                         const float* __restrict__ dinv, const float* __restrict__ b,
                         const float* __restrict__ H, float* __restrict__ out, int N) {
    int node = blockIdx.x * (TPB / 32) + (threadIdx.x >> 5);
    int f = threadIdx.x & 31;
    if (node >= N) return;
    float dv = dinv[node];
    float hv = H[(size_t)node * H1 + f];
    float acc;
    if (RELU) acc = fmaxf(hv, 0.0f) * dv * dv;
    else      acc = fmaf(hv, dv * dv, b[f]);
    int j = rowptr[node];
    int end = j + degi[node];
    for (; j + 1 < end; j += 2) {
        int s0 = csr_src[j], s1 = csr_src[j + 1];
        float c0 = csr_coef[j], c1 = csr_coef[j + 1];
        float v0 = H[(size_t)s0 * H1 + f];
        float v1 = H[(size_t)s1 * H1 + f];
        if (RELU) { v0 = fmaxf(v0, 0.0f); v1 = fmaxf(v1, 0.0f); }
        acc = fmaf(v0, c0, acc);
        acc = fmaf(v1, c1, acc);
    }
    if (j < end) {
        float v = H[(size_t)csr_src[j] * H1 + f];
        if (RELU) v = fmaxf(v, 0.0f);
        acc = fmaf(v, csr_coef[j], acc);
    }
    out[(size_t)node * H1 + f] = acc;
}

// ---------------- L2 GEMM (32->64) with fused z = relu(acc+b2) . w3l ----------------
__global__ void gemm2_z(const float* __restrict__ S1, const float* __restrict__ W2,
                        const float* __restrict__ b2, const float* __restrict__ w3l,
                        float* __restrict__ z, int N) {
    __shared__ float Ws[H1 * 64];
    for (int t = threadIdx.x; t < H1 * 64; t += blockDim.x) Ws[t] = W2[t];
    __syncthreads();
    const int c = threadIdx.x & 63;   // one wave per row
    const int r = threadIdx.x >> 6;   // 4 rows per block
    const float wl = w3l[c];
    const float bias = b2[c];
    for (int base = blockIdx.x * 4; base < N; base += gridDim.x * 4) {
        int row = base + r;
        if (row >= N) continue;
        const float* xr = S1 + (size_t)row * H1;
        float acc = 0.0f;
#pragma unroll
        for (int k = 0; k < H1; ++k) acc = fmaf(xr[k], Ws[k * 64 + c], acc);
        float p = fmaxf(acc + bias, 0.0f) * wl;
#pragma unroll
        for (int o = 32; o > 0; o >>= 1) p += __shfl_down(p, o);
        if (c == 0) z[row] = p;
    }
}

// ---------------- L3 gather (scalar) fused with segment-mean pooling ----------------
__global__ void gather_z_pool(const int* __restrict__ rowptr, const int* __restrict__ degi,
                              const int* __restrict__ csr_src, const float* __restrict__ csr_coef,
                              const float* __restrict__ dinv, const float* __restrict__ z,
                              const int* __restrict__ batch, float* __restrict__ sums,
                              float* __restrict__ cnt, int N, int G) {
    __shared__ float accS[TPB];
    __shared__ float cntS[TPB];
    accS[threadIdx.x] = 0.0f;
    cntS[threadIdx.x] = 0.0f;
    __syncthreads();
    int i = blockIdx.x * TPB + threadIdx.x;
    int first = blockIdx.x * TPB;
    int b0 = batch[first < N ? first : (N - 1)];
    if (i < N) {
        float dv = dinv[i];
        float val = z[i] * dv * dv;
        int j = rowptr[i];
        int end = j + degi[i];
        for (; j + 1 < end; j += 2) {
            float v0 = z[csr_src[j]] * csr_coef[j];
            float v1 = z[csr_src[j + 1]] * csr_coef[j + 1];
            val += v0 + v1;
        }
        if (j < end) val = fmaf(z[csr_src[j]], csr_coef[j], val);
        int off = batch[i] - b0;
        if (off < TPB) {
            atomicAdd(&accS[off], val);
            atomicAdd(&cntS[off], 1.0f);
        } else {
            atomicAdd(&sums[batch[i]], val);
            atomicAdd(&cnt[batch[i]], 1.0f);
        }
    }
    __syncthreads();
    int g = b0 + threadIdx.x;
    if (g < G) {
        if (accS[threadIdx.x] != 0.0f) atomicAdd(&sums[g], accS[threadIdx.x]);
        if (cntS[threadIdx.x] != 0.0f) atomicAdd(&cnt[g], cntS[threadIdx.x]);
    }
}

__global__ void out_kernel(const float* __restrict__ sums, const float* __restrict__ cnt,
                           const float* __restrict__ w3l, float* __restrict__ out, int G) {
    int g = blockIdx.x * blockDim.x + threadIdx.x;
    if (g < G) out[g] = sums[g] / fmaxf(cnt[g], 1.0f) + w3l[64];
}

static inline int grid_for(unsigned total, int cap = 8192) {
    unsigned g = (total + TPB - 1) / TPB;
    return (int)(g < (unsigned)cap ? g : (unsigned)cap);
}

extern "C" void kernel_launch(void* const* d_in, const int* in_sizes, int n_in,
                              void* d_out, int out_size, void* d_ws, size_t ws_size,
                              hipStream_t stream) {
    const float* x     = (const float*)d_in[0];
    const int*   ei    = (const int*)d_in[1];
    const int*   batch = (const int*)d_in[2];
    const float* W1    = (const float*)d_in[3];
    const float* b1    = (const float*)d_in[4];
    const float* W2    = (const float*)d_in[5];
    const float* b2    = (const float*)d_in[6];
    const float* W3    = (const float*)d_in[7];
    const float* b3    = (const float*)d_in[8];
    const float* Wl    = (const float*)d_in[9];
    const float* bl    = (const float*)d_in[10];
    float* out = (float*)d_out;

    const int N = in_sizes[0] / F_IN;  // 100000
    const int E = in_sizes[1] / 2;     // 1600000
    const int G = out_size;            // 1024
    const int* src = ei;
    const int* dst = ei + E;
    const int nb = (N + TPB - 1) / TPB;  // scan blocks (391 <= 512)

    // workspace layout
    int*   degi    = (int*)d_ws;                       // N
    int*   rowptr  = degi + N;                         // N
    int*   cursor  = rowptr + N;                       // N
    int*   bsum    = cursor + N;                       // 512
    int*   csr_src = bsum + 512;                       // E
    float* csr_coef= (float*)(csr_src + E);            // E
    float* dinv    = csr_coef + E;                     // N
    float* t1      = dinv + N;                         // N*32
    float* g1      = t1 + (size_t)N * H1;              // N*32
    float* s1      = g1 + (size_t)N * H1;              // N*32
    float* z       = s1 + (size_t)N * H1;              // N
    float* w3l     = z + N;                            // 72
    float* sums    = w3l + 72;                         // G
    float* cnt     = sums + G;                         // G

    hipMemsetAsync(degi, 0, (size_t)N * sizeof(int), stream);
    hipMemsetAsync(sums, 0, (size_t)2 * G * sizeof(float), stream);

    // degree -> CSR rowptr/cursor + dinv
    deg_kernel<<<grid_for(E), TPB, 0, stream>>>(dst, degi, E);
    scan1<<<nb, TPB, 0, stream>>>(degi, bsum, N);
    scan2<<<1, 512, 0, stream>>>(bsum, nb);
    scan3<<<nb, TPB, 0, stream>>>(degi, bsum, rowptr, cursor, dinv, N);
    fill_kernel<<<grid_for(E), TPB, 0, stream>>>(src, dst, dinv, cursor, csr_src, csr_coef, E);

    // fold last layer + head
    prep_kernel<<<1, 64, 0, stream>>>(W3, b3, Wl, bl, w3l);

    // L1: t1 = x@W1 ; g1 = gather(t1) + t1*d^2 + b1
    gemm1_kernel<<<grid_for((unsigned)N * H1), TPB, 0, stream>>>(x, W1, t1, N);
    gather32<false><<<(N + 7) / 8, TPB, 0, stream>>>(rowptr, degi, csr_src, csr_coef,
                                                     dinv, b1, t1, g1, N);

    // L2 aggregate: s1 = gather(relu(g1)) + relu(g1)*d^2
    gather32<true><<<(N + 7) / 8, TPB, 0, stream>>>(rowptr, degi, csr_src, csr_coef,
                                                    dinv, nullptr, g1, s1, N);

    // L2 transform + head fold: z = relu(s1@W2+b2) . w3l
    gemm2_z<<<grid_for((unsigned)N * 64), TPB, 0, stream>>>(s1, W2, b2, w3l, z, N);

    // L3 gather (scalar) + segment mean
    gather_z_pool<<<(N + TPB - 1) / TPB, TPB, 0, stream>>>(rowptr, degi, csr_src, csr_coef,
                                                           dinv, z, batch, sums, cnt, N, G);
    out_kernel<<<(G + TPB - 1) / TPB, TPB, 0, stream>>>(sums, cnt, w3l, out, G);
}

// Round 5
// 415.076 us; speedup vs baseline: 6.7410x; 1.0180x over previous
//
#include <hip/hip_runtime.h>

static constexpr int F_IN = 128;
static constexpr int H1 = 32;
static constexpr int TPB = 256;

// ---------------- degree count (int) ----------------
__global__ void deg_kernel(const int* __restrict__ dst, int* __restrict__ degi, int E) {
    for (int i = blockIdx.x * blockDim.x + threadIdx.x; i < E; i += gridDim.x * blockDim.x)
        atomicAdd(&degi[dst[i]], 1);
}

// ---------------- prefix scan (3 passes) for CSR rowptr ----------------
__global__ void scan1(const int* __restrict__ degi, int* __restrict__ bsum, int N) {
    __shared__ int sh[TPB];
    int i = blockIdx.x * TPB + threadIdx.x;
    sh[threadIdx.x] = (i < N) ? degi[i] : 0;
    __syncthreads();
    for (int o = TPB / 2; o > 0; o >>= 1) {
        if (threadIdx.x < o) sh[threadIdx.x] += sh[threadIdx.x + o];
        __syncthreads();
    }
    if (threadIdx.x == 0) bsum[blockIdx.x] = sh[0];
}

__global__ void scan2(int* __restrict__ bsum, int nb) {  // nb <= 512, one block of 512
    __shared__ int sh[512];
    int t = threadIdx.x;
    int orig = (t < nb) ? bsum[t] : 0;
    sh[t] = orig;
    __syncthreads();
    for (int o = 1; o < 512; o <<= 1) {
        int v = (t >= o) ? sh[t - o] : 0;
        __syncthreads();
        sh[t] += v;
        __syncthreads();
    }
    if (t < nb) bsum[t] = sh[t] - orig;  // exclusive
}

__global__ void scan3(const int* __restrict__ degi, const int* __restrict__ bsum,
                      int* __restrict__ rowptr, int* __restrict__ cursor,
                      float* __restrict__ dinv, int N) {
    __shared__ int sh[TPB];
    int i = blockIdx.x * TPB + threadIdx.x;
    int t = threadIdx.x;
    int d = (i < N) ? degi[i] : 0;
    sh[t] = d;
    __syncthreads();
    for (int o = 1; o < TPB; o <<= 1) {
        int v = (t >= o) ? sh[t - o] : 0;
        __syncthreads();
        sh[t] += v;
        __syncthreads();
    }
    if (i < N) {
        int excl = sh[t] - d + bsum[blockIdx.x];
        rowptr[i] = excl;
        cursor[i] = excl;
        dinv[i] = 1.0f / sqrtf((float)d + 1.0f);  // deg incl. self-loop
    }
}

// ---------------- CSR fill: bucket src indices by dst (single 4B payload) ----------------
__global__ void fill_kernel(const int* __restrict__ src, const int* __restrict__ dst,
                            int* __restrict__ cursor, int* __restrict__ csr_src, int E) {
    for (int i = blockIdx.x * blockDim.x + threadIdx.x; i < E; i += gridDim.x * blockDim.x) {
        int s = src[i], d = dst[i];
        int slot = atomicAdd(&cursor[d], 1);
        csr_src[slot] = s;
    }
}

// ---------------- fold W3 @ W_lin -> w3l[64], w3l[64] = beta ----------------
__global__ void prep_kernel(const float* __restrict__ W3, const float* __restrict__ b3,
                            const float* __restrict__ Wl, const float* __restrict__ bl,
                            float* __restrict__ w3l) {
    int j = threadIdx.x;  // 64 threads
    float acc = 0.0f;
#pragma unroll
    for (int k = 0; k < 128; ++k) acc = fmaf(W3[j * 128 + k], Wl[k], acc);
    w3l[j] = acc;
    if (j == 0) {
        float beta = bl[0];
        for (int f = 0; f < 128; ++f) beta = fmaf(b3[f], Wl[f], beta);
        w3l[64] = beta;
    }
}

// ---------------- L1 GEMM: t1p = (x@W1) * dinv[row]  (row-prescaled) ----------------
__global__ void gemm1_kernel(const float* __restrict__ X, const float* __restrict__ W,
                             const float* __restrict__ dinv, float* __restrict__ T, int N) {
    __shared__ float Ws[F_IN * H1];
    for (int t = threadIdx.x; t < F_IN * H1; t += blockDim.x) Ws[t] = W[t];
    __syncthreads();
    constexpr int ROWS = TPB / H1;  // 8
    const int c = threadIdx.x % H1;
    const int r = threadIdx.x / H1;
    for (int base = blockIdx.x * ROWS; base < N; base += gridDim.x * ROWS) {
        int row = base + r;
        if (row >= N) continue;
        const float4* xr = reinterpret_cast<const float4*>(X + (size_t)row * F_IN);
        float acc = 0.0f;
#pragma unroll
        for (int k4 = 0; k4 < F_IN / 4; ++k4) {
            float4 xv = xr[k4];
            acc = fmaf(xv.x, Ws[(k4 * 4 + 0) * H1 + c], acc);
            acc = fmaf(xv.y, Ws[(k4 * 4 + 1) * H1 + c], acc);
            acc = fmaf(xv.z, Ws[(k4 * 4 + 2) * H1 + c], acc);
            acc = fmaf(xv.w, Ws[(k4 * 4 + 3) * H1 + c], acc);
        }
        T[(size_t)row * H1 + c] = acc * dinv[row];
    }
}

// ---------------- pass 1 gather: g1p = relu(dv*(sum t1p[s] + t1p[d]) + b1) * dv ----------
__global__ void gatherA(const int* __restrict__ rowptr, const int* __restrict__ degi,
                        const int* __restrict__ csr_src, const float* __restrict__ dinv,
                        const float* __restrict__ b, const float* __restrict__ H,
                        float* __restrict__ out, int N) {
    int node = blockIdx.x * (TPB / 32) + (threadIdx.x >> 5);
    int f = threadIdx.x & 31;
    if (node >= N) return;
    float dv = dinv[node];
    float acc = H[(size_t)node * H1 + f];  // self (prescaled)
    int j = rowptr[node];
    int end = j + degi[node];
    for (; j + 1 < end; j += 2) {
        float v0 = H[(size_t)csr_src[j] * H1 + f];
        float v1 = H[(size_t)csr_src[j + 1] * H1 + f];
        acc += v0 + v1;
    }
    if (j < end) acc += H[(size_t)csr_src[j] * H1 + f];
    float g = fmaf(acc, dv, b[f]);
    out[(size_t)node * H1 + f] = fmaxf(g, 0.0f) * dv;
}

// ---------------- pass 2 gather fused with gemm2 + head fold ----------------
// s1[f] = dv*(sum g1p[s,f] + g1p[d,f]) ; z = sum_c relu(s1.W2[:,c]+b2[c])*w3l[c] ; zp = z*dv
__global__ void gatherB(const int* __restrict__ rowptr, const int* __restrict__ degi,
                        const int* __restrict__ csr_src, const float* __restrict__ dinv,
                        const float* __restrict__ G1p, const float* __restrict__ W2,
                        const float* __restrict__ b2, const float* __restrict__ w3l,
                        float* __restrict__ zp, int N) {
    __shared__ float W2s[H1 * 64];
    __shared__ float bw[64];
    __shared__ float wl[64];
    for (int t = threadIdx.x; t < H1 * 64; t += blockDim.x) W2s[t] = W2[t];
    if (threadIdx.x < 64) {
        bw[threadIdx.x] = b2[threadIdx.x];
        wl[threadIdx.x] = w3l[threadIdx.x];
    }
    __syncthreads();
    int node = blockIdx.x * (TPB / 32) + (threadIdx.x >> 5);
    int f = threadIdx.x & 31;
    if (node >= N) return;
    float dv = dinv[node];
    float acc = G1p[(size_t)node * H1 + f];
    int j = rowptr[node];
    int end = j + degi[node];
    for (; j + 1 < end; j += 2) {
        float v0 = G1p[(size_t)csr_src[j] * H1 + f];
        float v1 = G1p[(size_t)csr_src[j + 1] * H1 + f];
        acc += v0 + v1;
    }
    if (j < end) acc += G1p[(size_t)csr_src[j] * H1 + f];
    float s1 = acc * dv;
    // matvec: each lane handles columns f and f+32
    float d0 = bw[f], d1 = bw[f + 32];
#pragma unroll
    for (int k = 0; k < H1; ++k) {
        float sv = __shfl(s1, k, 32);
        d0 = fmaf(sv, W2s[k * 64 + f], d0);
        d1 = fmaf(sv, W2s[k * 64 + f + 32], d1);
    }
    float p = fmaxf(d0, 0.0f) * wl[f] + fmaxf(d1, 0.0f) * wl[f + 32];
#pragma unroll
    for (int o = 16; o > 0; o >>= 1) p += __shfl_down(p, o, 32);
    if (f == 0) zp[node] = p * dv;
}

// ---------------- pass 3 scalar gather fused with segment-mean pooling ----------------
__global__ void gather_z_pool(const int* __restrict__ rowptr, const int* __restrict__ degi,
                              const int* __restrict__ csr_src, const float* __restrict__ dinv,
                              const float* __restrict__ zp, const int* __restrict__ batch,
                              float* __restrict__ sums, float* __restrict__ cnt, int N, int G) {
    __shared__ float accS[TPB];
    __shared__ float cntS[TPB];
    accS[threadIdx.x] = 0.0f;
    cntS[threadIdx.x] = 0.0f;
    __syncthreads();
    int i = blockIdx.x * TPB + threadIdx.x;
    int first = blockIdx.x * TPB;
    int b0 = batch[first < N ? first : (N - 1)];
    if (i < N) {
        float acc = zp[i];  // self (prescaled)
        int j = rowptr[i];
        int end = j + degi[i];
        for (; j + 1 < end; j += 2) acc += zp[csr_src[j]] + zp[csr_src[j + 1]];
        if (j < end) acc += zp[csr_src[j]];
        float val = acc * dinv[i];
        int off = batch[i] - b0;
        if (off < TPB) {
            atomicAdd(&accS[off], val);
            atomicAdd(&cntS[off], 1.0f);
        } else {
            atomicAdd(&sums[batch[i]], val);
            atomicAdd(&cnt[batch[i]], 1.0f);
        }
    }
    __syncthreads();
    int g = b0 + threadIdx.x;
    if (g < G) {
        if (accS[threadIdx.x] != 0.0f) atomicAdd(&sums[g], accS[threadIdx.x]);
        if (cntS[threadIdx.x] != 0.0f) atomicAdd(&cnt[g], cntS[threadIdx.x]);
    }
}

__global__ void out_kernel(const float* __restrict__ sums, const float* __restrict__ cnt,
                           const float* __restrict__ w3l, float* __restrict__ out, int G) {
    int g = blockIdx.x * blockDim.x + threadIdx.x;
    if (g < G) out[g] = sums[g] / fmaxf(cnt[g], 1.0f) + w3l[64];
}

static inline int grid_for(unsigned total, int cap = 8192) {
    unsigned g = (total + TPB - 1) / TPB;
    return (int)(g < (unsigned)cap ? g : (unsigned)cap);
}

extern "C" void kernel_launch(void* const* d_in, const int* in_sizes, int n_in,
                              void* d_out, int out_size, void* d_ws, size_t ws_size,
                              hipStream_t stream) {
    const float* x     = (const float*)d_in[0];
    const int*   ei    = (const int*)d_in[1];
    const int*   batch = (const int*)d_in[2];
    const float* W1    = (const float*)d_in[3];
    const float* b1    = (const float*)d_in[4];
    const float* W2    = (const float*)d_in[5];
    const float* b2    = (const float*)d_in[6];
    const float* W3    = (const float*)d_in[7];
    const float* b3    = (const float*)d_in[8];
    const float* Wl    = (const float*)d_in[9];
    const float* bl    = (const float*)d_in[10];
    float* out = (float*)d_out;

    const int N = in_sizes[0] / F_IN;  // 100000
    const int E = in_sizes[1] / 2;     // 1600000
    const int G = out_size;            // 1024
    const int* src = ei;
    const int* dst = ei + E;
    const int nb = (N + TPB - 1) / TPB;  // scan blocks (391 <= 512)

    // workspace layout
    int*   degi    = (int*)d_ws;                       // N
    int*   rowptr  = degi + N;                         // N
    int*   cursor  = rowptr + N;                       // N
    int*   bsum    = cursor + N;                       // 512
    int*   csr_src = bsum + 512;                       // E
    float* dinv    = (float*)(csr_src + E);            // N
    float* t1p     = dinv + N;                         // N*32
    float* g1p     = t1p + (size_t)N * H1;             // N*32
    float* zp      = g1p + (size_t)N * H1;             // N
    float* w3l     = zp + N;                           // 72
    float* sums    = w3l + 72;                         // G
    float* cnt     = sums + G;                         // G

    hipMemsetAsync(degi, 0, (size_t)N * sizeof(int), stream);
    hipMemsetAsync(sums, 0, (size_t)2 * G * sizeof(float), stream);

    // degree -> CSR rowptr/cursor + dinv
    deg_kernel<<<grid_for(E), TPB, 0, stream>>>(dst, degi, E);
    scan1<<<nb, TPB, 0, stream>>>(degi, bsum, N);
    scan2<<<1, 512, 0, stream>>>(bsum, nb);
    scan3<<<nb, TPB, 0, stream>>>(degi, bsum, rowptr, cursor, dinv, N);
    fill_kernel<<<grid_for(E), TPB, 0, stream>>>(src, dst, cursor, csr_src, E);

    // fold last layer + head
    prep_kernel<<<1, 64, 0, stream>>>(W3, b3, Wl, bl, w3l);

    // L1: t1p = (x@W1)*dinv
    gemm1_kernel<<<grid_for((unsigned)N * H1), TPB, 0, stream>>>(x, W1, dinv, t1p, N);

    // pass 1: g1p = relu(A-row-sum + b1) * dinv
    gatherA<<<(N + 7) / 8, TPB, 0, stream>>>(rowptr, degi, csr_src, dinv, b1, t1p, g1p, N);

    // pass 2: fused gather + gemm2 + head fold -> zp
    gatherB<<<(N + 7) / 8, TPB, 0, stream>>>(rowptr, degi, csr_src, dinv, g1p, W2, b2, w3l, zp, N);

    // pass 3: scalar gather + segment mean
    gather_z_pool<<<(N + TPB - 1) / TPB, TPB, 0, stream>>>(rowptr, degi, csr_src, dinv, zp,
                                                           batch, sums, cnt, N, G);
    out_kernel<<<(G + TPB - 1) / TPB, TPB, 0, stream>>>(sums, cnt, w3l, out, G);
}

// Round 6
// 363.647 us; speedup vs baseline: 7.6943x; 1.1414x over previous
//
#include <hip/hip_runtime.h>

static constexpr int F_IN = 128;
static constexpr int H1 = 32;
static constexpr int TPB = 256;

// ---------------- degree count (int) ----------------
__global__ void deg_kernel(const int* __restrict__ dst, int* __restrict__ degi, int E) {
    for (int i = blockIdx.x * blockDim.x + threadIdx.x; i < E; i += gridDim.x * blockDim.x)
        atomicAdd(&degi[dst[i]], 1);
}

// ---------------- prefix scan (3 passes) for CSR rowptr ----------------
__global__ void scan1(const int* __restrict__ degi, int* __restrict__ bsum, int N) {
    __shared__ int sh[TPB];
    int i = blockIdx.x * TPB + threadIdx.x;
    sh[threadIdx.x] = (i < N) ? degi[i] : 0;
    __syncthreads();
    for (int o = TPB / 2; o > 0; o >>= 1) {
        if (threadIdx.x < o) sh[threadIdx.x] += sh[threadIdx.x + o];
        __syncthreads();
    }
    if (threadIdx.x == 0) bsum[blockIdx.x] = sh[0];
}

__global__ void scan2(int* __restrict__ bsum, int nb) {  // nb <= 512, one block of 512
    __shared__ int sh[512];
    int t = threadIdx.x;
    int orig = (t < nb) ? bsum[t] : 0;
    sh[t] = orig;
    __syncthreads();
    for (int o = 1; o < 512; o <<= 1) {
        int v = (t >= o) ? sh[t - o] : 0;
        __syncthreads();
        sh[t] += v;
        __syncthreads();
    }
    if (t < nb) bsum[t] = sh[t] - orig;  // exclusive
}

__global__ void scan3(const int* __restrict__ degi, const int* __restrict__ bsum,
                      int* __restrict__ rowptr, int* __restrict__ cursor,
                      float* __restrict__ dinv, int N) {
    __shared__ int sh[TPB];
    int i = blockIdx.x * TPB + threadIdx.x;
    int t = threadIdx.x;
    int d = (i < N) ? degi[i] : 0;
    sh[t] = d;
    __syncthreads();
    for (int o = 1; o < TPB; o <<= 1) {
        int v = (t >= o) ? sh[t - o] : 0;
        __syncthreads();
        sh[t] += v;
        __syncthreads();
    }
    if (i < N) {
        int excl = sh[t] - d + bsum[blockIdx.x];
        rowptr[i] = excl;
        cursor[i] = excl;
        dinv[i] = 1.0f / sqrtf((float)d + 1.0f);  // deg incl. self-loop
    }
}

// ---------------- CSR fill, XCD-bucketed ----------------
// blockIdx%8 ~ XCD (round-robin dispatch). Class r handles dst in [lo,hi) only, so
// each XCD's L2 exclusively owns its cursor/csr_src slice -> full-line writebacks.
__global__ void fill_bucketed(const int* __restrict__ src, const int* __restrict__ dst,
                              int* __restrict__ cursor, int* __restrict__ csr_src,
                              int E, int N) {
    const int r = blockIdx.x & 7;
    const int b8 = blockIdx.x >> 3;
    const int nb8 = gridDim.x >> 3;        // blocks per class
    const int chunk = N >> 3;
    const int lo = r * chunk;
    const int hi = (r == 7) ? N : lo + chunk;
    for (int i = b8 * blockDim.x + threadIdx.x; i < E; i += nb8 * blockDim.x) {
        int d = dst[i];
        if (d >= lo && d < hi) {
            int slot = atomicAdd(&cursor[d], 1);
            csr_src[slot] = src[i];
        }
    }
}

// ---------------- fold W3 @ W_lin -> w3l[64], w3l[64] = beta ----------------
__global__ void prep_kernel(const float* __restrict__ W3, const float* __restrict__ b3,
                            const float* __restrict__ Wl, const float* __restrict__ bl,
                            float* __restrict__ w3l) {
    int j = threadIdx.x;  // 64 threads
    float acc = 0.0f;
#pragma unroll
    for (int k = 0; k < 128; ++k) acc = fmaf(W3[j * 128 + k], Wl[k], acc);
    w3l[j] = acc;
    if (j == 0) {
        float beta = bl[0];
        for (int f = 0; f < 128; ++f) beta = fmaf(b3[f], Wl[f], beta);
        w3l[64] = beta;
    }
}

// ---------------- L1 GEMM: t1p = (x@W1) * dinv[row]  (row-prescaled) ----------------
__global__ void gemm1_kernel(const float* __restrict__ X, const float* __restrict__ W,
                             const float* __restrict__ dinv, float* __restrict__ T, int N) {
    __shared__ float Ws[F_IN * H1];
    for (int t = threadIdx.x; t < F_IN * H1; t += blockDim.x) Ws[t] = W[t];
    __syncthreads();
    constexpr int ROWS = TPB / H1;  // 8
    const int c = threadIdx.x % H1;
    const int r = threadIdx.x / H1;
    for (int base = blockIdx.x * ROWS; base < N; base += gridDim.x * ROWS) {
        int row = base + r;
        if (row >= N) continue;
        const float4* xr = reinterpret_cast<const float4*>(X + (size_t)row * F_IN);
        float acc = 0.0f;
#pragma unroll
        for (int k4 = 0; k4 < F_IN / 4; ++k4) {
            float4 xv = xr[k4];
            acc = fmaf(xv.x, Ws[(k4 * 4 + 0) * H1 + c], acc);
            acc = fmaf(xv.y, Ws[(k4 * 4 + 1) * H1 + c], acc);
            acc = fmaf(xv.z, Ws[(k4 * 4 + 2) * H1 + c], acc);
            acc = fmaf(xv.w, Ws[(k4 * 4 + 3) * H1 + c], acc);
        }
        T[(size_t)row * H1 + c] = acc * dinv[row];
    }
}

// ---------------- pass 1 gather: g1p = relu(dv*(sum t1p[s] + t1p[d]) + b1) * dv ----------
__global__ void gatherA(const int* __restrict__ rowptr, const int* __restrict__ degi,
                        const int* __restrict__ csr_src, const float* __restrict__ dinv,
                        const float* __restrict__ b, const float* __restrict__ H,
                        float* __restrict__ out, int N) {
    int node = blockIdx.x * (TPB / 32) + (threadIdx.x >> 5);
    int f = threadIdx.x & 31;
    if (node >= N) return;
    float dv = dinv[node];
    float acc = H[(size_t)node * H1 + f];  // self (prescaled)
    int j = rowptr[node];
    int end = j + degi[node];
    for (; j + 1 < end; j += 2) {
        float v0 = H[(size_t)csr_src[j] * H1 + f];
        float v1 = H[(size_t)csr_src[j + 1] * H1 + f];
        acc += v0 + v1;
    }
    if (j < end) acc += H[(size_t)csr_src[j] * H1 + f];
    float g = fmaf(acc, dv, b[f]);
    out[(size_t)node * H1 + f] = fmaxf(g, 0.0f) * dv;
}

// ---------------- pass 2 gather fused with gemm2 + head fold ----------------
// s1[f] = dv*(sum g1p[s,f] + g1p[d,f]) ; z = sum_c relu(s1.W2[:,c]+b2[c])*w3l[c] ; zp = z*dv
__global__ void gatherB(const int* __restrict__ rowptr, const int* __restrict__ degi,
                        const int* __restrict__ csr_src, const float* __restrict__ dinv,
                        const float* __restrict__ G1p, const float* __restrict__ W2,
                        const float* __restrict__ b2, const float* __restrict__ w3l,
                        float* __restrict__ zp, int N) {
    __shared__ float W2s[H1 * 64];
    __shared__ float bw[64];
    __shared__ float wl[64];
    for (int t = threadIdx.x; t < H1 * 64; t += blockDim.x) W2s[t] = W2[t];
    if (threadIdx.x < 64) {
        bw[threadIdx.x] = b2[threadIdx.x];
        wl[threadIdx.x] = w3l[threadIdx.x];
    }
    __syncthreads();
    int node = blockIdx.x * (TPB / 32) + (threadIdx.x >> 5);
    int f = threadIdx.x & 31;
    if (node >= N) return;
    float dv = dinv[node];
    float acc = G1p[(size_t)node * H1 + f];
    int j = rowptr[node];
    int end = j + degi[node];
    for (; j + 1 < end; j += 2) {
        float v0 = G1p[(size_t)csr_src[j] * H1 + f];
        float v1 = G1p[(size_t)csr_src[j + 1] * H1 + f];
        acc += v0 + v1;
    }
    if (j < end) acc += G1p[(size_t)csr_src[j] * H1 + f];
    float s1 = acc * dv;
    // matvec: each lane handles columns f and f+32
    float d0 = bw[f], d1 = bw[f + 32];
#pragma unroll
    for (int k = 0; k < H1; ++k) {
        float sv = __shfl(s1, k, 32);
        d0 = fmaf(sv, W2s[k * 64 + f], d0);
        d1 = fmaf(sv, W2s[k * 64 + f + 32], d1);
    }
    float p = fmaxf(d0, 0.0f) * wl[f] + fmaxf(d1, 0.0f) * wl[f + 32];
#pragma unroll
    for (int o = 16; o > 0; o >>= 1) p += __shfl_down(p, o, 32);
    if (f == 0) zp[node] = p * dv;
}

// ---------------- pass 3 scalar gather fused with segment-mean pooling ----------------
__global__ void gather_z_pool(const int* __restrict__ rowptr, const int* __restrict__ degi,
                              const int* __restrict__ csr_src, const float* __restrict__ dinv,
                              const float* __restrict__ zp, const int* __restrict__ batch,
                              float* __restrict__ sums, float* __restrict__ cnt, int N, int G) {
    __shared__ float accS[TPB];
    __shared__ float cntS[TPB];
    accS[threadIdx.x] = 0.0f;
    cntS[threadIdx.x] = 0.0f;
    __syncthreads();
    int i = blockIdx.x * TPB + threadIdx.x;
    int first = blockIdx.x * TPB;
    int b0 = batch[first < N ? first : (N - 1)];
    if (i < N) {
        float acc = zp[i];  // self (prescaled)
        int j = rowptr[i];
        int end = j + degi[i];
        for (; j + 1 < end; j += 2) acc += zp[csr_src[j]] + zp[csr_src[j + 1]];
        if (j < end) acc += zp[csr_src[j]];
        float val = acc * dinv[i];
        int off = batch[i] - b0;
        if (off < TPB) {
            atomicAdd(&accS[off], val);
            atomicAdd(&cntS[off], 1.0f);
        } else {
            atomicAdd(&sums[batch[i]], val);
            atomicAdd(&cnt[batch[i]], 1.0f);
        }
    }
    __syncthreads();
    int g = b0 + threadIdx.x;
    if (g < G) {
        if (accS[threadIdx.x] != 0.0f) atomicAdd(&sums[g], accS[threadIdx.x]);
        if (cntS[threadIdx.x] != 0.0f) atomicAdd(&cnt[g], cntS[threadIdx.x]);
    }
}

__global__ void out_kernel(const float* __restrict__ sums, const float* __restrict__ cnt,
                           const float* __restrict__ w3l, float* __restrict__ out, int G) {
    int g = blockIdx.x * blockDim.x + threadIdx.x;
    if (g < G) out[g] = sums[g] / fmaxf(cnt[g], 1.0f) + w3l[64];
}

static inline int grid_for(unsigned total, int cap = 8192) {
    unsigned g = (total + TPB - 1) / TPB;
    return (int)(g < (unsigned)cap ? g : (unsigned)cap);
}

extern "C" void kernel_launch(void* const* d_in, const int* in_sizes, int n_in,
                              void* d_out, int out_size, void* d_ws, size_t ws_size,
                              hipStream_t stream) {
    const float* x     = (const float*)d_in[0];
    const int*   ei    = (const int*)d_in[1];
    const int*   batch = (const int*)d_in[2];
    const float* W1    = (const float*)d_in[3];
    const float* b1    = (const float*)d_in[4];
    const float* W2    = (const float*)d_in[5];
    const float* b2    = (const float*)d_in[6];
    const float* W3    = (const float*)d_in[7];
    const float* b3    = (const float*)d_in[8];
    const float* Wl    = (const float*)d_in[9];
    const float* bl    = (const float*)d_in[10];
    float* out = (float*)d_out;

    const int N = in_sizes[0] / F_IN;  // 100000
    const int E = in_sizes[1] / 2;     // 1600000
    const int G = out_size;            // 1024
    const int* src = ei;
    const int* dst = ei + E;
    const int nb = (N + TPB - 1) / TPB;  // scan blocks (391 <= 512)

    // workspace layout
    int*   degi    = (int*)d_ws;                       // N
    int*   rowptr  = degi + N;                         // N
    int*   cursor  = rowptr + N;                       // N
    int*   bsum    = cursor + N;                       // 512
    int*   csr_src = bsum + 512;                       // E
    float* dinv    = (float*)(csr_src + E);            // N
    float* t1p     = dinv + N;                         // N*32
    float* g1p     = t1p + (size_t)N * H1;             // N*32
    float* zp      = g1p + (size_t)N * H1;             // N
    float* w3l     = zp + N;                           // 72
    float* sums    = w3l + 72;                         // G
    float* cnt     = sums + G;                         // G

    hipMemsetAsync(degi, 0, (size_t)N * sizeof(int), stream);
    hipMemsetAsync(sums, 0, (size_t)2 * G * sizeof(float), stream);

    // degree -> CSR rowptr/cursor + dinv
    deg_kernel<<<grid_for(E), TPB, 0, stream>>>(dst, degi, E);
    scan1<<<nb, TPB, 0, stream>>>(degi, bsum, N);
    scan2<<<1, 512, 0, stream>>>(bsum, nb);
    scan3<<<nb, TPB, 0, stream>>>(degi, bsum, rowptr, cursor, dinv, N);
    // XCD-bucketed fill: 2048 blocks (multiple of 8)
    fill_bucketed<<<2048, TPB, 0, stream>>>(src, dst, cursor, csr_src, E, N);

    // fold last layer + head
    prep_kernel<<<1, 64, 0, stream>>>(W3, b3, Wl, bl, w3l);

    // L1: t1p = (x@W1)*dinv
    gemm1_kernel<<<grid_for((unsigned)N * H1), TPB, 0, stream>>>(x, W1, dinv, t1p, N);

    // pass 1: g1p = relu(A-row-sum + b1) * dinv
    gatherA<<<(N + 7) / 8, TPB, 0, stream>>>(rowptr, degi, csr_src, dinv, b1, t1p, g1p, N);

    // pass 2: fused gather + gemm2 + head fold -> zp
    gatherB<<<(N + 7) / 8, TPB, 0, stream>>>(rowptr, degi, csr_src, dinv, g1p, W2, b2, w3l, zp, N);

    // pass 3: scalar gather + segment mean
    gather_z_pool<<<(N + TPB - 1) / TPB, TPB, 0, stream>>>(rowptr, degi, csr_src, dinv, zp,
                                                           batch, sums, cnt, N, G);
    out_kernel<<<(G + TPB - 1) / TPB, TPB, 0, stream>>>(sums, cnt, w3l, out, G);
}